// Round 6
// baseline (257.858 us; speedup 1.0000x reference)
//
#include <hip/hip_runtime.h>
#include <cmath>

#define BB   2
#define LL   2048
#define DIMD 1024
#define NS   16
#define KC   4
#define ML   (BB*LL)        // 4096 rows (B*L)
#define XZ_N (2*DIMD)       // 2048
#define XD_N (2*NS + DIMD)  // 1056
#define LC   16             // scan chunk length
#define NC   (LL/LC)        // 128 chunks per sequence

typedef __attribute__((ext_vector_type(8))) short bf16x8;   // 8 bf16 (4 VGPRs)
typedef __attribute__((ext_vector_type(4))) float f32x4;    // MFMA acc

__device__ __forceinline__ unsigned short f2bf(float f) {
    union { float f; unsigned u; } v; v.f = f;
    unsigned r = v.u + 0x7FFF + ((v.u >> 16) & 1);   // round-to-nearest-even
    return (unsigned short)(r >> 16);
}

// ---------------------------------------------------------------------------
// Fused f32 -> bf16 conversion for x + the 3 weight matrices (one launch).
// ---------------------------------------------------------------------------
__global__ __launch_bounds__(256) void cvt_all(
    const float* __restrict__ s0, unsigned short* __restrict__ d0, int n0,
    const float* __restrict__ s1, unsigned short* __restrict__ d1, int n1,
    const float* __restrict__ s2, unsigned short* __restrict__ d2, int n2,
    const float* __restrict__ s3, unsigned short* __restrict__ d3, int n3)
{
    int i = blockIdx.x * blockDim.x + threadIdx.x;
    const float* src; unsigned short* dst;
    if (i < n0)                { src = s0; dst = d0; }
    else if ((i -= n0) < n1)   { src = s1; dst = d1; }
    else if ((i -= n1) < n2)   { src = s2; dst = d2; }
    else if ((i -= n2) < n3)   { src = s3; dst = d3; }
    else return;
    float4 f = ((const float4*)src)[i];
    ushort4 o;
    o.x = f2bf(f.x); o.y = f2bf(f.y); o.z = f2bf(f.z); o.w = f2bf(f.w);
    ((ushort4*)dst)[i] = o;
}

// ---------------------------------------------------------------------------
// bf16 MFMA GEMM, C[M,N] = A[M,K] @ W[N,K]^T (both row-major, K contiguous).
// 128x128 tile, BK=64, 4 waves x 64x64, mfma_f32_16x16x32_bf16 4x4 frags.
// global_load_lds width=16 staging with XOR-8 chunk swizzle. (unchanged)
// ---------------------------------------------------------------------------
__global__ __launch_bounds__(256) void gemm_mfma_bt(
    const unsigned short* __restrict__ A,
    const unsigned short* __restrict__ Bw,
    float* __restrict__ C,
    int M, int N, int K)
{
    __shared__ short As[128 * 64];
    __shared__ short Bs[128 * 64];

    const int tid  = threadIdx.x;
    const int lane = tid & 63;
    const int wave = tid >> 6;
    const int bm = blockIdx.y * 128;
    const int bn = blockIdx.x * 128;
    const int wm = (wave >> 1) * 64;
    const int wn = (wave & 1) * 64;
    const int l15  = lane & 15;
    const int quad = lane >> 4;

    f32x4 acc[4][4];
    #pragma unroll
    for (int i = 0; i < 4; ++i)
        #pragma unroll
        for (int j = 0; j < 4; ++j)
            acc[i][j] = (f32x4){0.f, 0.f, 0.f, 0.f};

    for (int k0 = 0; k0 < K; k0 += 64) {
        __syncthreads();
        #pragma unroll
        for (int q = 0; q < 4; ++q) {
            const int ci = q * 256 + tid;
            const int r  = ci >> 3;
            const int cc = (ci & 7) ^ (r & 7);
            short* ldsA = As + (size_t)(q * 256 + (tid & ~63)) * 8;
            short* ldsB = Bs + (size_t)(q * 256 + (tid & ~63)) * 8;
            const unsigned short* ga = A + (size_t)(bm + r) * K + k0 + cc * 8;
            int rb = bn + r; if (rb > N - 1) rb = N - 1;
            const unsigned short* gb = Bw + (size_t)rb * K + k0 + cc * 8;
            __builtin_amdgcn_global_load_lds(
                (const __attribute__((address_space(1))) void*)ga,
                (__attribute__((address_space(3))) void*)ldsA, 16, 0, 0);
            __builtin_amdgcn_global_load_lds(
                (const __attribute__((address_space(1))) void*)gb,
                (__attribute__((address_space(3))) void*)ldsB, 16, 0, 0);
        }
        __syncthreads();

        #pragma unroll
        for (int kh = 0; kh < 2; ++kh) {
            bf16x8 af[4], bfr[4];
            #pragma unroll
            for (int i = 0; i < 4; ++i) {
                const int row = wm + i * 16 + l15;
                const int pc  = (kh * 4 + quad) ^ (row & 7);
                af[i] = *(const bf16x8*)(As + row * 64 + pc * 8);
            }
            #pragma unroll
            for (int j = 0; j < 4; ++j) {
                const int row = wn + j * 16 + l15;
                const int pc  = (kh * 4 + quad) ^ (row & 7);
                bfr[j] = *(const bf16x8*)(Bs + row * 64 + pc * 8);
            }
            #pragma unroll
            for (int i = 0; i < 4; ++i)
                #pragma unroll
                for (int j = 0; j < 4; ++j)
                    acc[i][j] = __builtin_amdgcn_mfma_f32_16x16x32_bf16(
                        af[i], bfr[j], acc[i][j], 0, 0, 0);
        }
    }

    #pragma unroll
    for (int i = 0; i < 4; ++i) {
        const int rbase = bm + wm + i * 16 + quad * 4;
        #pragma unroll
        for (int j = 0; j < 4; ++j) {
            const int col = bn + wn + j * 16 + l15;
            if (col < N) {
                #pragma unroll
                for (int r = 0; r < 4; ++r)
                    C[(size_t)(rbase + r) * N + col] = acc[i][j][r];
            }
        }
    }
}

// ---------------------------------------------------------------------------
// Depthwise causal conv (K=4) + bias + SiLU; writes f32 + bf16.
// ---------------------------------------------------------------------------
__global__ __launch_bounds__(256) void conv_silu(const float* __restrict__ xz,
                                                 const float* __restrict__ w,
                                                 const float* __restrict__ bias,
                                                 float* __restrict__ xc,
                                                 unsigned short* __restrict__ xcb)
{
    const int idx = blockIdx.x * blockDim.x + threadIdx.x;
    if (idx >= ML * DIMD) return;
    const int d  = idx & (DIMD - 1);
    const int bl = idx >> 10;
    const int l  = bl & (LL - 1);

    float acc = bias[d];
    const float* p = xz + (size_t)bl * XZ_N + d;
    #pragma unroll
    for (int t = 0; t < KC; ++t) {
        const int ls = l - (KC - 1) + t;
        if (ls >= 0)
            acc = fmaf(w[d * KC + t], p[(long)(t - (KC - 1)) * XZ_N], acc);
    }
    const float v = acc / (1.f + expf(-acc));
    xc[idx] = v;
    xcb[idx] = f2bf(v);
}

__device__ __forceinline__ float softplus_f(float x) {
    return (x > 20.f) ? x : log1pf(expf(x));
}

// ---------------------------------------------------------------------------
// Scan pass 1: block = 256 d-lanes of one (b,chunk). B rows staged in LDS,
// consumed as explicit float4 components (register-resident, no local array).
// Four e^4-stepped p-chains for ILP. Emit h[16] + S=sum(dt).
// ---------------------------------------------------------------------------
__global__ __launch_bounds__(256) void scan_part1(const float* __restrict__ xdbl,
                                                  const float* __restrict__ xc,
                                                  float* __restrict__ hfin,
                                                  float* __restrict__ Ssum)
{
    __shared__ float Bsh[LC][NS];   // 1 KB

    const int tid = threadIdx.x;
    const int idx = blockIdx.x * 256 + tid;   // global (b,c,d)
    const int d   = idx & (DIMD - 1);
    const int bc  = idx >> 10;
    const int c   = bc & (NC - 1);
    const int b   = bc >> 7;
    const int l0  = c * LC;

    const float* xdbl_p = xdbl + ((size_t)b * LL + l0) * XD_N;
    const float* xc_p   = xc   + ((size_t)b * LL + l0) * DIMD + d;

    if (tid < LC * NS / 4) {               // 64 threads stage 16x16 B block
        const int l = tid >> 2, q = tid & 3;
        ((float4*)&Bsh[l][0])[q] = ((const float4*)(xdbl_p + (size_t)l * XD_N))[q];
    }
    __syncthreads();

    float h[NS];
    #pragma unroll
    for (int n = 0; n < NS; ++n) h[n] = 0.f;
    float S = 0.f;

    for (int i = 0; i < LC; ++i) {
        const float dt = softplus_f(xdbl_p[(size_t)i * XD_N + 2 * NS + d]);
        S += dt;
        const float e  = expf(-dt);
        const float dx = dt * xc_p[(size_t)i * DIMD];

        const float4* BC = (const float4*)&Bsh[i][0];
        const float4 B0 = BC[0], B1 = BC[1], B2 = BC[2], B3 = BC[3];

        const float e2 = e * e, e4 = e2 * e2;
        float p0 = e, p1 = e2, p2 = e2 * e, p3 = e4;   // e^1..e^4
        h[0]  = fmaf(h[0],  p0, dx * B0.x);
        h[1]  = fmaf(h[1],  p1, dx * B0.y);
        h[2]  = fmaf(h[2],  p2, dx * B0.z);
        h[3]  = fmaf(h[3],  p3, dx * B0.w);
        p0 *= e4; p1 *= e4; p2 *= e4; p3 *= e4;        // e^5..e^8
        h[4]  = fmaf(h[4],  p0, dx * B1.x);
        h[5]  = fmaf(h[5],  p1, dx * B1.y);
        h[6]  = fmaf(h[6],  p2, dx * B1.z);
        h[7]  = fmaf(h[7],  p3, dx * B1.w);
        p0 *= e4; p1 *= e4; p2 *= e4; p3 *= e4;        // e^9..e^12
        h[8]  = fmaf(h[8],  p0, dx * B2.x);
        h[9]  = fmaf(h[9],  p1, dx * B2.y);
        h[10] = fmaf(h[10], p2, dx * B2.z);
        h[11] = fmaf(h[11], p3, dx * B2.w);
        p0 *= e4; p1 *= e4; p2 *= e4; p3 *= e4;        // e^13..e^16
        h[12] = fmaf(h[12], p0, dx * B3.x);
        h[13] = fmaf(h[13], p1, dx * B3.y);
        h[14] = fmaf(h[14], p2, dx * B3.z);
        h[15] = fmaf(h[15], p3, dx * B3.w);
    }

    float4* hf = (float4*)(hfin + (size_t)idx * NS);
    #pragma unroll
    for (int n = 0; n < 4; ++n) hf[n] = ((float4*)h)[n];
    Ssum[idx] = S;
}

// ---------------------------------------------------------------------------
// Scan pass 2 (combine): thread per (b,d,n); hfin rewritten in place to
// carry-in states.
// ---------------------------------------------------------------------------
__global__ __launch_bounds__(256) void scan_combine(float* __restrict__ hfin,
                                                    const float* __restrict__ Ssum)
{
    const int idx = blockIdx.x * blockDim.x + threadIdx.x;  // B*DIMD*NS
    const int n = idx & (NS - 1);
    const int d = (idx >> 4) & (DIMD - 1);
    const int b = idx >> 14;
    const float np1 = (float)(n + 1);

    float h = 0.f;
    for (int c = 0; c < NC; ++c) {
        const size_t base = ((size_t)(b * NC + c) * DIMD + d);
        const float S   = Ssum[base];
        const size_t o  = base * NS + n;
        const float tmp = hfin[o];
        hfin[o] = h;
        h = fmaf(h, expf(-S * np1), tmp);
    }
}

// ---------------------------------------------------------------------------
// Scan pass 3: B+C staged in LDS, consumed as explicit float4 components;
// 4 partial y accumulators; y = sum(h*C) + D*xc, gate silu(z), store bf16.
// ---------------------------------------------------------------------------
__global__ __launch_bounds__(256) void scan_part2(const float* __restrict__ xdbl,
                                                  const float* __restrict__ xc,
                                                  const float* __restrict__ xz,
                                                  const float* __restrict__ hfin,
                                                  const float* __restrict__ Dp,
                                                  unsigned short* __restrict__ yout)
{
    __shared__ float BCs[LC][2 * NS];   // 2 KB: [l][0..15]=B, [l][16..31]=C

    const int tid = threadIdx.x;
    const int idx = blockIdx.x * 256 + tid;
    const int d   = idx & (DIMD - 1);
    const int bc  = idx >> 10;
    const int c   = bc & (NC - 1);
    const int b   = bc >> 7;
    const int l0  = c * LC;

    const float* xdbl_p = xdbl + ((size_t)b * LL + l0) * XD_N;
    const float* xc_p   = xc   + ((size_t)b * LL + l0) * DIMD + d;
    const float* xz_p   = xz   + ((size_t)b * LL + l0) * XZ_N + DIMD + d;
    unsigned short* y_p = yout + ((size_t)b * LL + l0) * DIMD + d;

    if (tid < LC * 2 * NS / 4) {           // 128 threads stage 16x32 B|C block
        const int l = tid >> 3, q = tid & 7;
        ((float4*)&BCs[l][0])[q] = ((const float4*)(xdbl_p + (size_t)l * XD_N))[q];
    }
    __syncthreads();

    const float Dv = Dp[d];
    float h[NS];
    {
        const float4* hf = (const float4*)(hfin + (size_t)idx * NS);
        #pragma unroll
        for (int n = 0; n < 4; ++n) ((float4*)h)[n] = hf[n];
    }

    for (int i = 0; i < LC; ++i) {
        const float dt  = softplus_f(xdbl_p[(size_t)i * XD_N + 2 * NS + d]);
        const float xcv = xc_p[(size_t)i * DIMD];
        const float zv  = xz_p[(size_t)i * XZ_N];

        const float e  = expf(-dt);
        const float dx = dt * xcv;

        const float4* BC = (const float4*)&BCs[i][0];
        const float4 B0 = BC[0], B1 = BC[1], B2 = BC[2], B3 = BC[3];
        const float4 C0 = BC[4], C1 = BC[5], C2 = BC[6], C3 = BC[7];

        const float e2 = e * e, e4 = e2 * e2;
        float p0 = e, p1 = e2, p2 = e2 * e, p3 = e4;   // e^1..e^4
        float y0, y1, y2, y3;
        h[0]  = fmaf(h[0],  p0, dx * B0.x); y0 = h[0]  * C0.x;
        h[1]  = fmaf(h[1],  p1, dx * B0.y); y1 = h[1]  * C0.y;
        h[2]  = fmaf(h[2],  p2, dx * B0.z); y2 = h[2]  * C0.z;
        h[3]  = fmaf(h[3],  p3, dx * B0.w); y3 = h[3]  * C0.w;
        p0 *= e4; p1 *= e4; p2 *= e4; p3 *= e4;        // e^5..e^8
        h[4]  = fmaf(h[4],  p0, dx * B1.x); y0 = fmaf(h[4],  C1.x, y0);
        h[5]  = fmaf(h[5],  p1, dx * B1.y); y1 = fmaf(h[5],  C1.y, y1);
        h[6]  = fmaf(h[6],  p2, dx * B1.z); y2 = fmaf(h[6],  C1.z, y2);
        h[7]  = fmaf(h[7],  p3, dx * B1.w); y3 = fmaf(h[7],  C1.w, y3);
        p0 *= e4; p1 *= e4; p2 *= e4; p3 *= e4;        // e^9..e^12
        h[8]  = fmaf(h[8],  p0, dx * B2.x); y0 = fmaf(h[8],  C2.x, y0);
        h[9]  = fmaf(h[9],  p1, dx * B2.y); y1 = fmaf(h[9],  C2.y, y1);
        h[10] = fmaf(h[10], p2, dx * B2.z); y2 = fmaf(h[10], C2.z, y2);
        h[11] = fmaf(h[11], p3, dx * B2.w); y3 = fmaf(h[11], C2.w, y3);
        p0 *= e4; p1 *= e4; p2 *= e4; p3 *= e4;        // e^13..e^16
        h[12] = fmaf(h[12], p0, dx * B3.x); y0 = fmaf(h[12], C3.x, y0);
        h[13] = fmaf(h[13], p1, dx * B3.y); y1 = fmaf(h[13], C3.y, y1);
        h[14] = fmaf(h[14], p2, dx * B3.z); y2 = fmaf(h[14], C3.z, y2);
        h[15] = fmaf(h[15], p3, dx * B3.w); y3 = fmaf(h[15], C3.w, y3);

        const float y  = (y0 + y1) + (y2 + y3);
        const float yv = fmaf(Dv, xcv, y);
        const float sz = zv / (1.f + expf(-zv));
        y_p[(size_t)i * DIMD] = f2bf(yv * sz);
    }
}

extern "C" void kernel_launch(void* const* d_in, const int* in_sizes, int n_in,
                              void* d_out, int out_size, void* d_ws, size_t ws_size,
                              hipStream_t stream)
{
    const float* x          = (const float*)d_in[0];
    const float* in_proj_w  = (const float*)d_in[1];
    const float* conv_w     = (const float*)d_in[2];
    const float* conv_b     = (const float*)d_in[3];
    const float* x_proj_w   = (const float*)d_in[4];
    const float* D_param    = (const float*)d_in[5];
    const float* out_proj_w = (const float*)d_in[6];
    float* out = (float*)d_out;

    // workspace layout (~88.6 MiB, same as R3)
    float* xz   = (float*)d_ws;                               // ML*XZ_N f32
    float* xc   = xz   + (size_t)ML * XZ_N;                   // ML*DIMD f32
    float* xdbl = xc   + (size_t)ML * DIMD;                   // ML*XD_N f32
    unsigned short* xb  = (unsigned short*)(xdbl + (size_t)ML * XD_N); // ML*DIMD
    unsigned short* xcb = xb  + (size_t)ML * DIMD;            // ML*DIMD bf16
    unsigned short* wb1 = xcb + (size_t)ML * DIMD;            // XZ_N*DIMD bf16
    unsigned short* wb2 = wb1 + (size_t)XZ_N * DIMD;          // XD_N*DIMD bf16
    unsigned short* wb3 = wb2 + (size_t)XD_N * DIMD;          // DIMD*DIMD bf16
    unsigned short* yb  = xb;    // xb dead after GEMM1; reuse for scan output

    // hfin: B*NC*DIMD*NS floats = 16.8 MB = exact fit in d_out (dead till GEMM3)
    float* hfin = out;
    // Ssum: 1 MB, aliases wb1 (dead after GEMM1; scan runs after GEMM2)
    float* Ssum = (float*)wb1;

    const int n0 = ML * DIMD / 4, n1 = XZ_N * DIMD / 4,
              n2 = XD_N * DIMD / 4, n3 = DIMD * DIMD / 4;
    const int ncvt = n0 + n1 + n2 + n3;

    // 0) all f32->bf16 conversions in one launch
    cvt_all<<<(ncvt + 255) / 256, 256, 0, stream>>>(
        x, xb, n0, in_proj_w, wb1, n1, x_proj_w, wb2, n2, out_proj_w, wb3, n3);

    // 1) xz = x @ in_proj_w.T        (4096 x 2048 x 1024)
    gemm_mfma_bt<<<dim3(XZ_N / 128, ML / 128), 256, 0, stream>>>(
        xb, wb1, xz, ML, XZ_N, DIMD);

    // 2) depthwise conv + bias + silu -> xc (f32) + xcb (bf16)
    conv_silu<<<(ML * DIMD) / 256, 256, 0, stream>>>(xz, conv_w, conv_b, xc, xcb);

    // 3) x_dbl = xc @ x_proj_w.T     (4096 x 1056 x 1024)
    gemm_mfma_bt<<<dim3((XD_N + 127) / 128, ML / 128), 256, 0, stream>>>(
        xcb, wb2, xdbl, ML, XD_N, DIMD);

    // 4) chunked selective scan (LC=16 -> 1024 blocks for part1/part2)
    scan_part1<<<(BB * NC * DIMD) / 256, 256, 0, stream>>>(xdbl, xc, hfin, Ssum);
    scan_combine<<<(BB * DIMD * NS) / 256, 256, 0, stream>>>(hfin, Ssum);
    scan_part2<<<(BB * NC * DIMD) / 256, 256, 0, stream>>>(xdbl, xc, xz, hfin,
                                                           D_param, yb);

    // 5) out = y @ out_proj_w.T      (4096 x 1024 x 1024)
    gemm_mfma_bt<<<dim3(DIMD / 128, ML / 128), 256, 0, stream>>>(
        yb, wb3, out, ML, DIMD, DIMD);
}

// Round 7
// 250.647 us; speedup vs baseline: 1.0288x; 1.0288x over previous
//
#include <hip/hip_runtime.h>
#include <cmath>

#define BB   2
#define LL   2048
#define DIMD 1024
#define NS   16
#define KC   4
#define ML   (BB*LL)        // 4096 rows (B*L)
#define XZ_N (2*DIMD)       // 2048
#define XD_N (2*NS + DIMD)  // 1056
#define LC   16             // scan chunk length
#define NC   (LL/LC)        // 128 chunks per sequence

typedef __attribute__((ext_vector_type(8))) short bf16x8;   // 8 bf16 (4 VGPRs)
typedef __attribute__((ext_vector_type(4))) float f32x4;    // MFMA acc

__device__ __forceinline__ unsigned short f2bf(float f) {
    union { float f; unsigned u; } v; v.f = f;
    unsigned r = v.u + 0x7FFF + ((v.u >> 16) & 1);   // round-to-nearest-even
    return (unsigned short)(r >> 16);
}
__device__ __forceinline__ float bf2f(unsigned short u) {
    union { unsigned u; float f; } v; v.u = (unsigned)u << 16;
    return v.f;
}

// ---------------------------------------------------------------------------
// Fused f32 -> bf16 conversion for x + the 3 weight matrices (one launch).
// ---------------------------------------------------------------------------
__global__ __launch_bounds__(256) void cvt_all(
    const float* __restrict__ s0, unsigned short* __restrict__ d0, int n0,
    const float* __restrict__ s1, unsigned short* __restrict__ d1, int n1,
    const float* __restrict__ s2, unsigned short* __restrict__ d2, int n2,
    const float* __restrict__ s3, unsigned short* __restrict__ d3, int n3)
{
    int i = blockIdx.x * blockDim.x + threadIdx.x;
    const float* src; unsigned short* dst;
    if (i < n0)                { src = s0; dst = d0; }
    else if ((i -= n0) < n1)   { src = s1; dst = d1; }
    else if ((i -= n1) < n2)   { src = s2; dst = d2; }
    else if ((i -= n2) < n3)   { src = s3; dst = d3; }
    else return;
    float4 f = ((const float4*)src)[i];
    ushort4 o;
    o.x = f2bf(f.x); o.y = f2bf(f.y); o.z = f2bf(f.z); o.w = f2bf(f.w);
    ((ushort4*)dst)[i] = o;
}

// ---------------------------------------------------------------------------
// bf16 MFMA GEMM, C = A[M,K] @ W[N,K]^T. 128x128 tile, BK=64, 4 waves,
// mfma_f32_16x16x32_bf16 4x4 frags, global_load_lds w=16, XOR-8 swizzle.
// Epilogue: cols < nsplit -> f32 store (row stride = nsplit);
//           nsplit <= col < N -> silu + bf16 store to zb (row stride DIMD).
// GEMM2/3 pass nsplit == N (pure f32 path).
// ---------------------------------------------------------------------------
__global__ __launch_bounds__(256) void gemm_mfma_bt(
    const unsigned short* __restrict__ A,
    const unsigned short* __restrict__ Bw,
    float* __restrict__ C,
    unsigned short* __restrict__ zb,
    int M, int N, int K, int nsplit)
{
    __shared__ short As[128 * 64];
    __shared__ short Bs[128 * 64];

    const int tid  = threadIdx.x;
    const int lane = tid & 63;
    const int wave = tid >> 6;
    const int bm = blockIdx.y * 128;
    const int bn = blockIdx.x * 128;
    const int wm = (wave >> 1) * 64;
    const int wn = (wave & 1) * 64;
    const int l15  = lane & 15;
    const int quad = lane >> 4;

    f32x4 acc[4][4];
    #pragma unroll
    for (int i = 0; i < 4; ++i)
        #pragma unroll
        for (int j = 0; j < 4; ++j)
            acc[i][j] = (f32x4){0.f, 0.f, 0.f, 0.f};

    for (int k0 = 0; k0 < K; k0 += 64) {
        __syncthreads();
        #pragma unroll
        for (int q = 0; q < 4; ++q) {
            const int ci = q * 256 + tid;
            const int r  = ci >> 3;
            const int cc = (ci & 7) ^ (r & 7);
            short* ldsA = As + (size_t)(q * 256 + (tid & ~63)) * 8;
            short* ldsB = Bs + (size_t)(q * 256 + (tid & ~63)) * 8;
            const unsigned short* ga = A + (size_t)(bm + r) * K + k0 + cc * 8;
            int rb = bn + r; if (rb > N - 1) rb = N - 1;
            const unsigned short* gb = Bw + (size_t)rb * K + k0 + cc * 8;
            __builtin_amdgcn_global_load_lds(
                (const __attribute__((address_space(1))) void*)ga,
                (__attribute__((address_space(3))) void*)ldsA, 16, 0, 0);
            __builtin_amdgcn_global_load_lds(
                (const __attribute__((address_space(1))) void*)gb,
                (__attribute__((address_space(3))) void*)ldsB, 16, 0, 0);
        }
        __syncthreads();

        #pragma unroll
        for (int kh = 0; kh < 2; ++kh) {
            bf16x8 af[4], bfr[4];
            #pragma unroll
            for (int i = 0; i < 4; ++i) {
                const int row = wm + i * 16 + l15;
                const int pc  = (kh * 4 + quad) ^ (row & 7);
                af[i] = *(const bf16x8*)(As + row * 64 + pc * 8);
            }
            #pragma unroll
            for (int j = 0; j < 4; ++j) {
                const int row = wn + j * 16 + l15;
                const int pc  = (kh * 4 + quad) ^ (row & 7);
                bfr[j] = *(const bf16x8*)(Bs + row * 64 + pc * 8);
            }
            #pragma unroll
            for (int i = 0; i < 4; ++i)
                #pragma unroll
                for (int j = 0; j < 4; ++j)
                    acc[i][j] = __builtin_amdgcn_mfma_f32_16x16x32_bf16(
                        af[i], bfr[j], acc[i][j], 0, 0, 0);
        }
    }

    #pragma unroll
    for (int i = 0; i < 4; ++i) {
        const int rbase = bm + wm + i * 16 + quad * 4;
        #pragma unroll
        for (int j = 0; j < 4; ++j) {
            const int col = bn + wn + j * 16 + l15;
            if (col < nsplit) {
                #pragma unroll
                for (int r = 0; r < 4; ++r)
                    C[(size_t)(rbase + r) * nsplit + col] = acc[i][j][r];
            } else if (col < N) {
                const int zc = col - nsplit;
                #pragma unroll
                for (int r = 0; r < 4; ++r) {
                    const float v = acc[i][j][r];
                    zb[(size_t)(rbase + r) * DIMD + zc] =
                        f2bf(v / (1.f + expf(-v)));
                }
            }
        }
    }
}

// ---------------------------------------------------------------------------
// Depthwise causal conv (K=4) + bias + SiLU, 4 channels per thread (float4).
// x_c now dense (row stride DIMD). conv_w rows for 4 consecutive channels
// are 4 contiguous float4s.
// ---------------------------------------------------------------------------
__global__ __launch_bounds__(256) void conv_silu(const float* __restrict__ xcraw,
                                                 const float* __restrict__ w,
                                                 const float* __restrict__ bias,
                                                 float* __restrict__ xc,
                                                 unsigned short* __restrict__ xcb)
{
    const int i4 = blockIdx.x * blockDim.x + threadIdx.x;  // ML*DIMD/4
    if (i4 >= ML * DIMD / 4) return;
    const int dq = i4 & (DIMD / 4 - 1);    // d/4
    const int bl = i4 >> 8;                // b*L + l
    const int l  = bl & (LL - 1);

    const float4 wq0 = ((const float4*)w)[dq * 4 + 0];   // taps for ch d+0
    const float4 wq1 = ((const float4*)w)[dq * 4 + 1];
    const float4 wq2 = ((const float4*)w)[dq * 4 + 2];
    const float4 wq3 = ((const float4*)w)[dq * 4 + 3];
    const float4 bv  = ((const float4*)bias)[dq];

    const float* p = xcraw + (size_t)bl * DIMD + dq * 4;
    const float4 z4 = make_float4(0.f, 0.f, 0.f, 0.f);
    const float4 x0 = (l >= 3) ? *(const float4*)(p - 3 * DIMD) : z4;
    const float4 x1 = (l >= 2) ? *(const float4*)(p - 2 * DIMD) : z4;
    const float4 x2 = (l >= 1) ? *(const float4*)(p - 1 * DIMD) : z4;
    const float4 x3 = *(const float4*)p;

    float4 a;
    a.x = bv.x + wq0.x*x0.x + wq0.y*x1.x + wq0.z*x2.x + wq0.w*x3.x;
    a.y = bv.y + wq1.x*x0.y + wq1.y*x1.y + wq1.z*x2.y + wq1.w*x3.y;
    a.z = bv.z + wq2.x*x0.z + wq2.y*x1.z + wq2.z*x2.z + wq2.w*x3.z;
    a.w = bv.w + wq3.x*x0.w + wq3.y*x1.w + wq3.z*x2.w + wq3.w*x3.w;

    float4 v;
    v.x = a.x / (1.f + expf(-a.x));
    v.y = a.y / (1.f + expf(-a.y));
    v.z = a.z / (1.f + expf(-a.z));
    v.w = a.w / (1.f + expf(-a.w));

    ((float4*)xc)[i4] = v;
    ushort4 o;
    o.x = f2bf(v.x); o.y = f2bf(v.y); o.z = f2bf(v.z); o.w = f2bf(v.w);
    ((ushort4*)xcb)[i4] = o;
}

__device__ __forceinline__ float softplus_f(float x) {
    return (x > 20.f) ? x : log1pf(expf(x));
}

// ---------------------------------------------------------------------------
// Scan pass 1: hoisted loads + transcendentals (16 independent chains),
// then the h-recursion with B from LDS. Emit h[16] + S=sum(dt).
// ---------------------------------------------------------------------------
__global__ __launch_bounds__(256) void scan_part1(const float* __restrict__ xdbl,
                                                  const float* __restrict__ xc,
                                                  float* __restrict__ hfin,
                                                  float* __restrict__ Ssum)
{
    __shared__ float Bsh[LC][NS];   // 1 KB

    const int tid = threadIdx.x;
    const int idx = blockIdx.x * 256 + tid;   // global (b,c,d)
    const int d   = idx & (DIMD - 1);
    const int bc  = idx >> 10;
    const int c   = bc & (NC - 1);
    const int b   = bc >> 7;
    const int l0  = c * LC;

    const float* xdbl_p = xdbl + ((size_t)b * LL + l0) * XD_N;
    const float* xc_p   = xc   + ((size_t)b * LL + l0) * DIMD + d;

    if (tid < LC * NS / 4) {               // 64 threads stage 16x16 B block
        const int l = tid >> 2, q = tid & 3;
        ((float4*)&Bsh[l][0])[q] = ((const float4*)(xdbl_p + (size_t)l * XD_N))[q];
    }
    __syncthreads();

    // hoisted global loads (all 16 steps in flight)
    float raw[LC], xcv[LC];
    #pragma unroll
    for (int i = 0; i < LC; ++i) raw[i] = xdbl_p[(size_t)i * XD_N + 2 * NS + d];
    #pragma unroll
    for (int i = 0; i < LC; ++i) xcv[i] = xc_p[(size_t)i * DIMD];

    // hoisted transcendentals (16 independent chains)
    float e[LC], dx[LC];
    float S = 0.f;
    #pragma unroll
    for (int i = 0; i < LC; ++i) {
        const float dt = softplus_f(raw[i]);
        S += dt;
        e[i]  = expf(-dt);
        dx[i] = dt * xcv[i];
    }

    float h[NS];
    #pragma unroll
    for (int n = 0; n < NS; ++n) h[n] = 0.f;

    #pragma unroll
    for (int i = 0; i < LC; ++i) {
        const float4* BC = (const float4*)&Bsh[i][0];
        const float4 B0 = BC[0], B1 = BC[1], B2 = BC[2], B3 = BC[3];
        const float ev = e[i], dxv = dx[i];
        const float e2 = ev * ev, e4 = e2 * e2;
        float p0 = ev, p1 = e2, p2 = e2 * ev, p3 = e4;
        h[0]  = fmaf(h[0],  p0, dxv * B0.x);
        h[1]  = fmaf(h[1],  p1, dxv * B0.y);
        h[2]  = fmaf(h[2],  p2, dxv * B0.z);
        h[3]  = fmaf(h[3],  p3, dxv * B0.w);
        p0 *= e4; p1 *= e4; p2 *= e4; p3 *= e4;
        h[4]  = fmaf(h[4],  p0, dxv * B1.x);
        h[5]  = fmaf(h[5],  p1, dxv * B1.y);
        h[6]  = fmaf(h[6],  p2, dxv * B1.z);
        h[7]  = fmaf(h[7],  p3, dxv * B1.w);
        p0 *= e4; p1 *= e4; p2 *= e4; p3 *= e4;
        h[8]  = fmaf(h[8],  p0, dxv * B2.x);
        h[9]  = fmaf(h[9],  p1, dxv * B2.y);
        h[10] = fmaf(h[10], p2, dxv * B2.z);
        h[11] = fmaf(h[11], p3, dxv * B2.w);
        p0 *= e4; p1 *= e4; p2 *= e4; p3 *= e4;
        h[12] = fmaf(h[12], p0, dxv * B3.x);
        h[13] = fmaf(h[13], p1, dxv * B3.y);
        h[14] = fmaf(h[14], p2, dxv * B3.z);
        h[15] = fmaf(h[15], p3, dxv * B3.w);
    }

    float4* hf = (float4*)(hfin + (size_t)idx * NS);
    #pragma unroll
    for (int n = 0; n < 4; ++n) hf[n] = ((float4*)h)[n];
    Ssum[idx] = S;
}

// ---------------------------------------------------------------------------
// Scan pass 2 (combine): thread per (b,d,n); hfin rewritten in place to
// carry-in states.
// ---------------------------------------------------------------------------
__global__ __launch_bounds__(256) void scan_combine(float* __restrict__ hfin,
                                                    const float* __restrict__ Ssum)
{
    const int idx = blockIdx.x * blockDim.x + threadIdx.x;  // B*DIMD*NS
    const int n = idx & (NS - 1);
    const int d = (idx >> 4) & (DIMD - 1);
    const int b = idx >> 14;
    const float np1 = (float)(n + 1);

    float h = 0.f;
    for (int c = 0; c < NC; ++c) {
        const size_t base = ((size_t)(b * NC + c) * DIMD + d);
        const float S   = Ssum[base];
        const size_t o  = base * NS + n;
        const float tmp = hfin[o];
        hfin[o] = h;
        h = fmaf(h, expf(-S * np1), tmp);
    }
}

// ---------------------------------------------------------------------------
// Scan pass 3: hoisted loads/transcendentals; B+C from LDS; carry-in from
// hfin; y = sum(h*C) + D*xc, gate with PRE-COMPUTED silu(z) (bf16 zb from
// GEMM1 epilogue), store bf16.
// ---------------------------------------------------------------------------
__global__ __launch_bounds__(256) void scan_part2(const float* __restrict__ xdbl,
                                                  const float* __restrict__ xc,
                                                  const unsigned short* __restrict__ zb,
                                                  const float* __restrict__ hfin,
                                                  const float* __restrict__ Dp,
                                                  unsigned short* __restrict__ yout)
{
    __shared__ float BCs[LC][2 * NS];   // 2 KB

    const int tid = threadIdx.x;
    const int idx = blockIdx.x * 256 + tid;
    const int d   = idx & (DIMD - 1);
    const int bc  = idx >> 10;
    const int c   = bc & (NC - 1);
    const int b   = bc >> 7;
    const int l0  = c * LC;

    const float* xdbl_p = xdbl + ((size_t)b * LL + l0) * XD_N;
    const float* xc_p   = xc   + ((size_t)b * LL + l0) * DIMD + d;
    const unsigned short* zb_p = zb + ((size_t)b * LL + l0) * DIMD + d;
    unsigned short* y_p = yout + ((size_t)b * LL + l0) * DIMD + d;

    if (tid < LC * 2 * NS / 4) {           // 128 threads stage 16x32 B|C block
        const int l = tid >> 3, q = tid & 7;
        ((float4*)&BCs[l][0])[q] = ((const float4*)(xdbl_p + (size_t)l * XD_N))[q];
    }
    __syncthreads();

    // hoisted global loads
    float raw[LC], xcv[LC], zg[LC];
    #pragma unroll
    for (int i = 0; i < LC; ++i) raw[i] = xdbl_p[(size_t)i * XD_N + 2 * NS + d];
    #pragma unroll
    for (int i = 0; i < LC; ++i) xcv[i] = xc_p[(size_t)i * DIMD];
    #pragma unroll
    for (int i = 0; i < LC; ++i) zg[i] = bf2f(zb_p[(size_t)i * DIMD]);

    // hoisted transcendentals
    float e[LC], dx[LC];
    #pragma unroll
    for (int i = 0; i < LC; ++i) {
        const float dt = softplus_f(raw[i]);
        e[i]  = expf(-dt);
        dx[i] = dt * xcv[i];
    }

    const float Dv = Dp[d];
    float h[NS];
    {
        const float4* hf = (const float4*)(hfin + (size_t)idx * NS);
        #pragma unroll
        for (int n = 0; n < 4; ++n) ((float4*)h)[n] = hf[n];
    }

    #pragma unroll
    for (int i = 0; i < LC; ++i) {
        const float4* BC = (const float4*)&BCs[i][0];
        const float4 B0 = BC[0], B1 = BC[1], B2 = BC[2], B3 = BC[3];
        const float4 C0 = BC[4], C1 = BC[5], C2 = BC[6], C3 = BC[7];
        const float ev = e[i], dxv = dx[i];
        const float e2 = ev * ev, e4 = e2 * e2;
        float p0 = ev, p1 = e2, p2 = e2 * ev, p3 = e4;
        float y0, y1, y2, y3;
        h[0]  = fmaf(h[0],  p0, dxv * B0.x); y0 = h[0]  * C0.x;
        h[1]  = fmaf(h[1],  p1, dxv * B0.y); y1 = h[1]  * C0.y;
        h[2]  = fmaf(h[2],  p2, dxv * B0.z); y2 = h[2]  * C0.z;
        h[3]  = fmaf(h[3],  p3, dxv * B0.w); y3 = h[3]  * C0.w;
        p0 *= e4; p1 *= e4; p2 *= e4; p3 *= e4;
        h[4]  = fmaf(h[4],  p0, dxv * B1.x); y0 = fmaf(h[4],  C1.x, y0);
        h[5]  = fmaf(h[5],  p1, dxv * B1.y); y1 = fmaf(h[5],  C1.y, y1);
        h[6]  = fmaf(h[6],  p2, dxv * B1.z); y2 = fmaf(h[6],  C1.z, y2);
        h[7]  = fmaf(h[7],  p3, dxv * B1.w); y3 = fmaf(h[7],  C1.w, y3);
        p0 *= e4; p1 *= e4; p2 *= e4; p3 *= e4;
        h[8]  = fmaf(h[8],  p0, dxv * B2.x); y0 = fmaf(h[8],  C2.x, y0);
        h[9]  = fmaf(h[9],  p1, dxv * B2.y); y1 = fmaf(h[9],  C2.y, y1);
        h[10] = fmaf(h[10], p2, dxv * B2.z); y2 = fmaf(h[10], C2.z, y2);
        h[11] = fmaf(h[11], p3, dxv * B2.w); y3 = fmaf(h[11], C2.w, y3);
        p0 *= e4; p1 *= e4; p2 *= e4; p3 *= e4;
        h[12] = fmaf(h[12], p0, dxv * B3.x); y0 = fmaf(h[12], C3.x, y0);
        h[13] = fmaf(h[13], p1, dxv * B3.y); y1 = fmaf(h[13], C3.y, y1);
        h[14] = fmaf(h[14], p2, dxv * B3.z); y2 = fmaf(h[14], C3.z, y2);
        h[15] = fmaf(h[15], p3, dxv * B3.w); y3 = fmaf(h[15], C3.w, y3);

        const float y  = (y0 + y1) + (y2 + y3);
        const float yv = fmaf(Dv, xcv[i], y);
        y_p[(size_t)i * DIMD] = f2bf(yv * zg[i]);
    }
}

extern "C" void kernel_launch(void* const* d_in, const int* in_sizes, int n_in,
                              void* d_out, int out_size, void* d_ws, size_t ws_size,
                              hipStream_t stream)
{
    const float* x          = (const float*)d_in[0];
    const float* in_proj_w  = (const float*)d_in[1];
    const float* conv_w     = (const float*)d_in[2];
    const float* conv_b     = (const float*)d_in[3];
    const float* x_proj_w   = (const float*)d_in[4];
    const float* D_param    = (const float*)d_in[5];
    const float* out_proj_w = (const float*)d_in[6];
    float* out = (float*)d_out;

    // workspace layout (~84.5 MiB)
    float* xcraw = (float*)d_ws;                              // ML*DIMD f32 (x_c pre-conv)
    float* xc    = xcraw + (size_t)ML * DIMD;                 // ML*DIMD f32
    float* xdbl  = xc    + (size_t)ML * DIMD;                 // ML*XD_N f32
    unsigned short* zb  = (unsigned short*)(xdbl + (size_t)ML * XD_N); // ML*DIMD bf16 silu(z)
    unsigned short* xb  = zb  + (size_t)ML * DIMD;            // ML*DIMD bf16
    unsigned short* xcb = xb  + (size_t)ML * DIMD;            // ML*DIMD bf16
    unsigned short* wb1 = xcb + (size_t)ML * DIMD;            // XZ_N*DIMD bf16
    unsigned short* wb2 = wb1 + (size_t)XZ_N * DIMD;          // XD_N*DIMD bf16
    unsigned short* wb3 = wb2 + (size_t)XD_N * DIMD;          // DIMD*DIMD bf16
    unsigned short* yb  = xb;    // xb dead after GEMM1; reuse for scan output

    // hfin: B*NC*DIMD*NS floats = 16.8 MB = exact fit in d_out (dead till GEMM3)
    float* hfin = out;
    // Ssum: 1 MB, aliases wb1 (dead after GEMM1; scan runs after GEMM2)
    float* Ssum = (float*)wb1;

    const int n0 = ML * DIMD / 4, n1 = XZ_N * DIMD / 4,
              n2 = XD_N * DIMD / 4, n3 = DIMD * DIMD / 4;
    const int ncvt = n0 + n1 + n2 + n3;

    // 0) all f32->bf16 conversions in one launch
    cvt_all<<<(ncvt + 255) / 256, 256, 0, stream>>>(
        x, xb, n0, in_proj_w, wb1, n1, x_proj_w, wb2, n2, out_proj_w, wb3, n3);

    // 1) xz = x @ in_proj_w.T; x_c half -> f32 xcraw, z half -> silu bf16 zb
    gemm_mfma_bt<<<dim3(XZ_N / 128, ML / 128), 256, 0, stream>>>(
        xb, wb1, xcraw, zb, ML, XZ_N, DIMD, DIMD);

    // 2) depthwise conv + bias + silu -> xc (f32) + xcb (bf16), float4 wide
    conv_silu<<<(ML * DIMD / 4) / 256, 256, 0, stream>>>(
        xcraw, conv_w, conv_b, xc, xcb);

    // 3) x_dbl = xc @ x_proj_w.T     (4096 x 1056 x 1024)
    gemm_mfma_bt<<<dim3((XD_N + 127) / 128, ML / 128), 256, 0, stream>>>(
        xcb, wb2, xdbl, nullptr, ML, XD_N, DIMD, XD_N);

    // 4) chunked selective scan
    scan_part1<<<(BB * NC * DIMD) / 256, 256, 0, stream>>>(xdbl, xc, hfin, Ssum);
    scan_combine<<<(BB * DIMD * NS) / 256, 256, 0, stream>>>(hfin, Ssum);
    scan_part2<<<(BB * NC * DIMD) / 256, 256, 0, stream>>>(xdbl, xc, zb, hfin,
                                                           D_param, yb);

    // 5) out = y @ out_proj_w.T      (4096 x 1024 x 1024)
    gemm_mfma_bt<<<dim3(DIMD / 128, ML / 128), 256, 0, stream>>>(
        yb, wb3, out, nullptr, ML, DIMD, DIMD, DIMD);
}